// Round 2
// 223.332 us; speedup vs baseline: 1.0310x; 1.0310x over previous
//
#include <hip/hip_runtime.h>

#define S_VOX (128*128*128)   // spatial voxels per (b,n) plane = 2097152
#define QV (S_VOX/4)          // float4 groups per plane = 524288
#define EPSF 1e-10f
#define SMOOTHF 1e-5f

// ws layout (floats): [0] ce_sum, [1+ b*8+n] inter, [17+ b*8+n] ground, [33+ b*8+n] pred_o
#define NACC 49

__device__ __forceinline__ float wave_reduce(float v) {
#pragma unroll
    for (int off = 32; off > 0; off >>= 1)
        v += __shfl_down(v, off, 64);
    return v;
}

// One block handles ONE batch b (blockIdx parity). Per-thread live state:
// inter[8] + po[8] + ce (float) + gc[8] (int) = 25 accumulators -> no spills
// (the round-0 kernel kept 49 and spilled to scratch at VGPR_Count=48).
// CE decomposition:
//   ce_total = sum_{b,b',vox} log(pred[b, t[b',vox], vox] + EPS)
// so a batch-b block selects pred[b] at BOTH targets (own t[b] and other t[1-b]).
__global__ __launch_bounds__(256) void dice_main(const float* __restrict__ pred,
                                                 const int* __restrict__ tgt,
                                                 float* __restrict__ ws) {
    const int b   = blockIdx.x & 1;      // batch for this block
    const int bid = blockIdx.x >> 1;     // block index within batch group
    const int nbb = gridDim.x >> 1;      // blocks per batch

    const float4* p4   = (const float4*)pred + (size_t)b * 8u * (size_t)QV;
    const int4*   town = (const int4*)tgt + (size_t)b * (size_t)QV;
    const int4*   toth = (const int4*)tgt + (size_t)(1 - b) * (size_t)QV;

    float ce = 0.f;
    float inter[8], po[8];
    int   gc[8];
#pragma unroll
    for (int n = 0; n < 8; n++) { inter[n] = 0.f; po[n] = 0.f; gc[n] = 0; }

    const int tid0   = bid * blockDim.x + threadIdx.x;
    const int stride = nbb * blockDim.x;

    for (int q = tid0; q < QV; q += stride) {
        const int4 t0 = town[q];
        const int4 t1 = toth[q];
        // selected pred value at target class, per voxel slot
        float so0 = 0.f, so1 = 0.f, so2 = 0.f, so3 = 0.f;   // own target
        float st0 = 0.f, st1 = 0.f, st2 = 0.f, st3 = 0.f;   // other target
#pragma unroll
        for (int n = 0; n < 8; n++) {
            const float4 p = p4[(size_t)n * QV + q];
            po[n] += (p.x + p.y) + (p.z + p.w);

#define SLOT(pv, ta, tb, so, st)                                        \
            {                                                           \
                const bool m0 = ((ta) == n);                            \
                const bool m1 = ((tb) == n);                            \
                const float v0 = m0 ? (pv) : 0.f;                       \
                inter[n] += v0;                                         \
                so += v0;                                               \
                st += m1 ? (pv) : 0.f;                                  \
                gc[n] += (int)m0;                                       \
            }
            SLOT(p.x, t0.x, t1.x, so0, st0)
            SLOT(p.y, t0.y, t1.y, so1, st1)
            SLOT(p.z, t0.z, t1.z, so2, st2)
            SLOT(p.w, t0.w, t1.w, so3, st3)
#undef SLOT
        }
        // 8 logs per q-iter (vs 64 in round 0): log at the selected class only
        ce += __logf(so0 + EPSF) + __logf(st0 + EPSF);
        ce += __logf(so1 + EPSF) + __logf(st1 + EPSF);
        ce += __logf(so2 + EPSF) + __logf(st2 + EPSF);
        ce += __logf(so3 + EPSF) + __logf(st3 + EPSF);
    }

    // ---- block reduction: 25 scalars through the shuffle tree ----
    __shared__ float red[4][25];
    const int lane = threadIdx.x & 63;
    const int wave = threadIdx.x >> 6;

    float acc[25];
    acc[0] = ce;
#pragma unroll
    for (int n = 0; n < 8; n++) {
        acc[1 + n]  = inter[n];
        acc[9 + n]  = po[n];
        acc[17 + n] = (float)gc[n];
    }
#pragma unroll
    for (int i = 0; i < 25; i++) {
        float v = wave_reduce(acc[i]);
        if (lane == 0) red[wave][i] = v;
    }
    __syncthreads();

    const int i = threadIdx.x;
    if (i < 25) {
        float s = red[0][i] + red[1][i] + red[2][i] + red[3][i];
        int dst;
        if (i == 0)       dst = 0;                       // ce
        else if (i <= 8)  dst = 1  + b * 8 + (i - 1);    // inter
        else if (i <= 16) dst = 33 + b * 8 + (i - 9);    // pred_o
        else              dst = 17 + b * 8 + (i - 17);   // ground
        atomicAdd(&ws[dst], s);
    }
}

__global__ void dice_finalize(const float* __restrict__ ws, float* __restrict__ out) {
    const int i = threadIdx.x;
    float term = 0.f;
    if (i < 16) {
        float inter = ws[1 + i];
        float g     = ws[17 + i];
        float p     = ws[33 + i];
        term = 1.0f - (2.0f * inter + SMOOTHF) / (g + p + SMOOTHF);
    }
    term = wave_reduce(term);
    if (i == 0) {
        // celoss = -ce_sum / (B*B*S)  with B=2
        float celoss = -ws[0] / (4.0f * (float)S_VOX);
        out[0] = celoss + term * (1.0f / 16.0f);
    }
}

extern "C" void kernel_launch(void* const* d_in, const int* in_sizes, int n_in,
                              void* d_out, int out_size, void* d_ws, size_t ws_size,
                              hipStream_t stream) {
    const float* pred = (const float*)d_in[0];
    const int*   tgt  = (const int*)d_in[1];
    float* ws  = (float*)d_ws;
    float* out = (float*)d_out;

    hipMemsetAsync(ws, 0, NACC * sizeof(float), stream);
    // 2048 blocks: 1024 per batch -> stride 262144, exactly 2 q-iters/thread
    dice_main<<<2048, 256, 0, stream>>>(pred, tgt, ws);
    dice_finalize<<<1, 64, 0, stream>>>(ws, out);
}